// Round 7
// baseline (96.670 us; speedup 1.0000x reference)
//
#include <hip/hip_runtime.h>

typedef unsigned int uint32;
typedef unsigned short ushort;

typedef __bf16  bf16x8   __attribute__((ext_vector_type(8)));
typedef float   f32x4    __attribute__((ext_vector_type(4)));
typedef ushort  ushort4v __attribute__((ext_vector_type(4)));

#define K_CODES 1024
#define CDIM    64
#define HWALL   4096      // H*W
#define CHW     262144    // CDIM*HWALL
#define ROWS    64        // z-rows per block

__device__ __forceinline__ ushort f2bf(float f) {
    uint32 u = __builtin_bit_cast(uint32, f);
    u += 0x7FFFu + ((u >> 16) & 1u);   // RNE
    return (ushort)(u >> 16);
}

// Pass 0 (tiny): codebook fp32 -> bf16 row-major + negbias[k] = -0.5*||e_k||^2.
// Also zeroes the loss cell out[0].
__global__ __launch_bounds__(256) void prep_kernel(const float* __restrict__ cb,
                                                   ushort* __restrict__ cbb,
                                                   float* __restrict__ negbias,
                                                   float* __restrict__ out) {
    int t = threadIdx.x;
    if (blockIdx.x == 0 && t == 0) out[0] = 0.f;
    int k = blockIdx.x * 4 + (t >> 6);
    int c = t & 63;
    float v = cb[k * 64 + c];
    cbb[k * 64 + c] = f2bf(v);
    float s = v * v;
    #pragma unroll
    for (int d = 1; d < 64; d <<= 1) s += __shfl_xor(s, d, 64);
    if (c == 0) negbias[k] = -0.5f * s;
}

// Main: 1024 blocks x 512 threads (8 waves), TWO blocks/CU co-resident
// (VGPR<=128 via launch_bounds, LDS 11.3 KB) -- cross-block overlap hides the
// phase latency that 16-wave single-resident blocks (R4-R6) exposed.
// Block = 64 z-rows; wave w holds B-fragments for n-tiles [w*8,+8) in registers
// (64 VGPRs + 8 negbias), loaded once. Hot loop: A-frags from LDS + MFMA + pack.
__global__ __launch_bounds__(512, 4) void vq_kernel(const float* __restrict__ z,
                                                    const ushort* __restrict__ cbb,
                                                    const float* __restrict__ negbias,
                                                    const float* __restrict__ cb,
                                                    float* __restrict__ out) {
    __shared__ __align__(16) ushort Abf[ROWS * 72];   // 9 KB A-tile, pitch 72
    __shared__ float partial[8][ROWS];                // 2 KB packed argmax keys
    __shared__ float loss_acc;

    const int t   = threadIdx.x;
    const int blk = blockIdx.x;
    const int b   = blk >> 6;
    const int hw_base = (blk & 63) << 6;     // 64 groups of 64 rows
    const int zoff = b * CHW + hw_base;

    if (t == 0) loss_acc = 0.f;

    const int r  = t & 63;     // z-row (lanes consecutive -> coalesced 256B)
    const int cg = t >> 6;     // c-group 0..7 (== wave id)
    const int w  = t >> 6;     // wave 0..7: owns n-tiles [w*8, +8)
    const int l  = t & 63;
    const int m  = l & 15;     // B col within n-tile / A row within m-block
    const int q  = l >> 4;     // k-quad

    // ---- issue z loads (deepest dep) ----
    float zv[8];
    #pragma unroll
    for (int j = 0; j < 8; ++j) zv[j] = z[zoff + (cg * 8 + j) * HWALL + r];

    // ---- load this wave's codebook slice into registers (once) ----
    bf16x8 Bv[8][2];
    float  nb[8];
    #pragma unroll
    for (int j = 0; j < 8; ++j) {
        int col = (((w << 3) + j) << 4) + m;
        Bv[j][0] = *(const bf16x8*)&cbb[(col << 6) + (q << 3)];
        Bv[j][1] = *(const bf16x8*)&cbb[(col << 6) + 32 + (q << 3)];
        nb[j] = negbias[col];
    }

    // ---- stage z tile -> Abf (bf16, pitch 72) ----
    {
        ushort4v pk0, pk1;
        #pragma unroll
        for (int j = 0; j < 4; ++j) { pk0[j] = f2bf(zv[j]); pk1[j] = f2bf(zv[4 + j]); }
        *(ushort4v*)&Abf[r * 72 + cg * 8]     = pk0;
        *(ushort4v*)&Abf[r * 72 + cg * 8 + 4] = pk1;
    }
    __syncthreads();

    // ---- gemm: sweep all 4 m-blocks x this wave's 8 n-tiles ----
    float best[16];
    #pragma unroll
    for (int i = 0; i < 16; ++i) best[i] = -__builtin_inff();

    #pragma unroll
    for (int mb = 0; mb < 4; ++mb) {
        bf16x8 a0 = *(const bf16x8*)&Abf[(mb * 16 + m) * 72 + (q << 3)];
        bf16x8 a1 = *(const bf16x8*)&Abf[(mb * 16 + m) * 72 + 32 + (q << 3)];
        #pragma unroll
        for (int j = 0; j < 8; ++j) {
            uint32 tag = 1023u - (uint32)(((((w << 3) + j) << 4)) + m);
            f32x4 acc0;
            acc0[0] = nb[j]; acc0[1] = nb[j]; acc0[2] = nb[j]; acc0[3] = nb[j];
            f32x4 acc = __builtin_amdgcn_mfma_f32_16x16x32_bf16(a0, Bv[j][0], acc0, 0, 0, 0);
            acc       = __builtin_amdgcn_mfma_f32_16x16x32_bf16(a1, Bv[j][1], acc,  0, 0, 0);
            #pragma unroll
            for (int rr = 0; rr < 4; ++rr) {
                uint32 kb = (__builtin_bit_cast(uint32, acc[rr]) & 0xFFFFFC00u) | tag;
                best[mb * 4 + rr] = fmaxf(best[mb * 4 + rr], __builtin_bit_cast(float, kb));
            }
        }
    }

    // cross-lane argmax over the 16 cols (lanes sharing q)
    #pragma unroll
    for (int i = 0; i < 16; ++i) {
        float v = best[i];
        #pragma unroll
        for (int d = 1; d < 16; d <<= 1) v = fmaxf(v, __shfl_xor(v, d, 64));
        best[i] = v;
    }
    if (m == 0) {     // lanes q=0..3: rows mb*16 + q*4 + rr
        #pragma unroll
        for (int mb = 0; mb < 4; ++mb)
            #pragma unroll
            for (int rr = 0; rr < 4; ++rr)
                partial[w][mb * 16 + (q << 2) + rr] = best[mb * 4 + rr];
    }
    __syncthreads();

    // ---- writeback: 8-way combine, gather vq from L2-resident fp32 cb ----
    {
        float km = partial[0][r];
        #pragma unroll
        for (int j = 1; j < 8; ++j) km = fmaxf(km, partial[j][r]);
        int idx = 1023 - (int)(__builtin_bit_cast(uint32, km) & 1023u);

        const f32x4* crow = (const f32x4*)(cb + (idx << 6) + (cg << 3));
        f32x4 e0 = crow[0];
        f32x4 e1 = crow[1];
        ushort4v zb0 = *(const ushort4v*)&Abf[r * 72 + cg * 8];
        ushort4v zb1 = *(const ushort4v*)&Abf[r * 72 + cg * 8 + 4];

        float lsum = 0.f;
        #pragma unroll
        for (int j = 0; j < 4; ++j) {
            float v0  = e0[j];
            float v1  = e1[j];
            float zp0 = __builtin_bit_cast(float, (uint32)zb0[j] << 16);
            float zp1 = __builtin_bit_cast(float, (uint32)zb1[j] << 16);
            out[1 + zoff + (cg * 8 + j) * HWALL + r]     = v0;   // ST fwd == vq
            out[1 + zoff + (cg * 8 + 4 + j) * HWALL + r] = v1;
            float d0 = v0 - zp0, d1 = v1 - zp1;
            lsum += d0 * d0 + d1 * d1;
        }
        #pragma unroll
        for (int d = 1; d < 64; d <<= 1) lsum += __shfl_xor(lsum, d, 64);
        if (l == 0) atomicAdd(&loss_acc, lsum);
    }
    __syncthreads();
    if (t == 0) atomicAdd(out, loss_acc * (1.25f / 4194304.f));  // (1+BETA)/numel
}

extern "C" void kernel_launch(void* const* d_in, const int* in_sizes, int n_in,
                              void* d_out, int out_size, void* d_ws, size_t ws_size,
                              hipStream_t stream) {
    (void)in_sizes; (void)n_in; (void)out_size; (void)ws_size;
    const float* z  = (const float*)d_in[0];
    const float* cb = (const float*)d_in[1];
    float* out = (float*)d_out;
    ushort* cbb = (ushort*)d_ws;
    float* negbias = (float*)((char*)d_ws + K_CODES * CDIM * sizeof(ushort));

    prep_kernel<<<dim3(256), dim3(256), 0, stream>>>(cb, cbb, negbias, out);
    vq_kernel<<<dim3(1024), dim3(512), 0, stream>>>(z, cbb, negbias, cb, out);
}

// Round 8
// 88.167 us; speedup vs baseline: 1.0964x; 1.0964x over previous
//
#include <hip/hip_runtime.h>

typedef unsigned int uint32;
typedef unsigned short ushort;

typedef __bf16  bf16x8   __attribute__((ext_vector_type(8)));
typedef float   f32x4    __attribute__((ext_vector_type(4)));
typedef ushort  ushort4v __attribute__((ext_vector_type(4)));

#define K_CODES 1024
#define CDIM    64
#define HWALL   4096      // H*W
#define CHW     262144    // CDIM*HWALL
#define TROWS   128       // z-rows per tile (2 tiles per block)

__device__ __forceinline__ ushort f2bf(float f) {
    uint32 u = __builtin_bit_cast(uint32, f);
    u += 0x7FFFu + ((u >> 16) & 1u);   // RNE
    return (ushort)(u >> 16);
}

// Pass 0 (tiny): codebook fp32 -> bf16 row-major + negbias[k] = -0.5*||e_k||^2.
// Also zeroes the loss cell out[0].
__global__ __launch_bounds__(256) void prep_kernel(const float* __restrict__ cb,
                                                   ushort* __restrict__ cbb,
                                                   float* __restrict__ negbias,
                                                   float* __restrict__ out) {
    int t = threadIdx.x;
    if (blockIdx.x == 0 && t == 0) out[0] = 0.f;
    int k = blockIdx.x * 4 + (t >> 6);
    int c = t & 63;
    float v = cb[k * 64 + c];
    cbb[k * 64 + c] = f2bf(v);
    float s = v * v;
    #pragma unroll
    for (int d = 1; d < 64; d <<= 1) s += __shfl_xor(s, d, 64);
    if (c == 0) negbias[k] = -0.5f * s;
}

// Main: 256 blocks (1/CU) x 1024 threads (16 waves), TWO 128-row tiles per block,
// software-pipelined: tile-1 z loads issue before the first barrier and arrive
// during tile-0 GEMM; B-regs (wave w holds n-tiles [w*4,+4): 32 VGPRs + 4 nb)
// load ONCE per CU. Hot loop identical to R6 (no spills at ~105 VGPR).
// Gather uses bf16 codebook (1x16B divergent load); loss = 1 atomic per block.
__global__ __launch_bounds__(1024, 4) void vq_kernel(const float* __restrict__ z,
                                                     const ushort* __restrict__ cbb,
                                                     const float* __restrict__ negbias,
                                                     float* __restrict__ out) {
    __shared__ __align__(16) ushort Abf[TROWS * 72];  // 18 KB A-tile, pitch 72
    __shared__ float partial[16][TROWS];              // 8 KB packed argmax keys
    __shared__ float loss_acc;

    const int t   = threadIdx.x;
    const int blk = blockIdx.x;
    const int b   = blk >> 4;
    const int hw0 = (blk & 15) << 8;          // 256 rows per block
    const int zoff0 = b * CHW + hw0;

    if (t == 0) loss_acc = 0.f;

    const int r  = t & 127;    // z-row within tile (lanes consecutive -> coalesced)
    const int cg = t >> 7;     // c-group 0..7
    const int w  = t >> 6;     // wave 0..15: owns n-tiles [w*4, +4)
    const int l  = t & 63;
    const int m  = l & 15;     // B col within n-tile / A row within m-block
    const int q  = l >> 4;     // k-quad

    // ---- issue tile-0 z loads (deepest dep) ----
    float z0v[8];
    #pragma unroll
    for (int j = 0; j < 8; ++j) z0v[j] = z[zoff0 + (cg * 8 + j) * HWALL + r];

    // ---- load this wave's codebook slice into registers (once per CU) ----
    bf16x8 Bv[4][2];
    float  nb[4];
    #pragma unroll
    for (int j = 0; j < 4; ++j) {
        int col = (((w << 2) + j) << 4) + m;
        Bv[j][0] = *(const bf16x8*)&cbb[(col << 6) + (q << 3)];
        Bv[j][1] = *(const bf16x8*)&cbb[(col << 6) + 32 + (q << 3)];
        nb[j] = negbias[col];
    }

    // ---- issue tile-1 z loads now; they arrive during tile-0 GEMM ----
    float z1v[8];
    #pragma unroll
    for (int j = 0; j < 8; ++j) z1v[j] = z[zoff0 + 128 + (cg * 8 + j) * HWALL + r];

    // ---- stage tile-0 -> Abf (bf16, pitch 72) ----
    {
        ushort4v pk0, pk1;
        #pragma unroll
        for (int j = 0; j < 4; ++j) { pk0[j] = f2bf(z0v[j]); pk1[j] = f2bf(z0v[4 + j]); }
        *(ushort4v*)&Abf[r * 72 + cg * 8]     = pk0;
        *(ushort4v*)&Abf[r * 72 + cg * 8 + 4] = pk1;
    }
    __syncthreads();

    float lsum = 0.f;
    int zoffT = zoff0;
    #pragma unroll 1
    for (int T = 0; T < 2; ++T) {
        // ---- gemm: sweep 4 m-blocks x this wave's 4 n-tiles (reg-B) ----
        float best[16];
        #pragma unroll
        for (int i = 0; i < 16; ++i) best[i] = -__builtin_inff();

        #pragma unroll
        for (int mbb = 0; mbb < 8; ++mbb) {     // 8 m-blocks of 16 rows in 128
            bf16x8 a0 = *(const bf16x8*)&Abf[(mbb * 16 + m) * 72 + (q << 3)];
            bf16x8 a1 = *(const bf16x8*)&Abf[(mbb * 16 + m) * 72 + 32 + (q << 3)];
            #pragma unroll
            for (int j = 0; j < 4; ++j) {
                uint32 tag = 1023u - (uint32)(((((w << 2) + j) << 4)) + m);
                f32x4 acc0;
                acc0[0] = nb[j]; acc0[1] = nb[j]; acc0[2] = nb[j]; acc0[3] = nb[j];
                f32x4 acc = __builtin_amdgcn_mfma_f32_16x16x32_bf16(a0, Bv[j][0], acc0, 0, 0, 0);
                acc       = __builtin_amdgcn_mfma_f32_16x16x32_bf16(a1, Bv[j][1], acc,  0, 0, 0);
                #pragma unroll
                for (int rr = 0; rr < 4; ++rr) {
                    uint32 kb = (__builtin_bit_cast(uint32, acc[rr]) & 0xFFFFFC00u) | tag;
                    int bi = (mbb & 3) * 4 + rr;   // fold 8 mb into 16 keys per half
                    best[bi] = fmaxf(best[bi], __builtin_bit_cast(float, kb));
                }
                // NOTE: folding halves would merge different rows -- so split below
            }
            // write keys for this mb pair when the 4-row group completes
            if ((mbb & 3) == 3) {
                // reduce + store for m-blocks [mbb-3 .. mbb]
                #pragma unroll
                for (int i = 0; i < 16; ++i) {
                    float v = best[i];
                    #pragma unroll
                    for (int d = 1; d < 16; d <<= 1) v = fmaxf(v, __shfl_xor(v, d, 64));
                    best[i] = v;
                }
                if (m == 0) {
                    int base = (mbb - 3) * 16;
                    #pragma unroll
                    for (int mb2 = 0; mb2 < 4; ++mb2)
                        #pragma unroll
                        for (int rr = 0; rr < 4; ++rr)
                            partial[w][base + mb2 * 16 + (q << 2) + rr] = best[mb2 * 4 + rr];
                }
                #pragma unroll
                for (int i = 0; i < 16; ++i) best[i] = -__builtin_inff();
            }
        }
        __syncthreads();

        // ---- writeback: 16-way combine, gather vq from bf16 codebook ----
        {
            float km = partial[0][r];
            #pragma unroll
            for (int j = 1; j < 16; ++j) km = fmaxf(km, partial[j][r]);
            int idx = 1023 - (int)(__builtin_bit_cast(uint32, km) & 1023u);

            // single divergent 16B load: channels cg*8 .. cg*8+7 of code idx
            ushort4v ec0 = *(const ushort4v*)&cbb[(idx << 6) + (cg << 3)];
            ushort4v ec1 = *(const ushort4v*)&cbb[(idx << 6) + (cg << 3) + 4];
            ushort4v zb0 = *(const ushort4v*)&Abf[r * 72 + cg * 8];
            ushort4v zb1 = *(const ushort4v*)&Abf[r * 72 + cg * 8 + 4];

            #pragma unroll
            for (int j = 0; j < 4; ++j) {
                float v0  = __builtin_bit_cast(float, (uint32)ec0[j] << 16);
                float v1  = __builtin_bit_cast(float, (uint32)ec1[j] << 16);
                float zp0 = __builtin_bit_cast(float, (uint32)zb0[j] << 16);
                float zp1 = __builtin_bit_cast(float, (uint32)zb1[j] << 16);
                out[1 + zoffT + (cg * 8 + j) * HWALL + r]     = v0;   // ST fwd == vq
                out[1 + zoffT + (cg * 8 + 4 + j) * HWALL + r] = v1;
                float d0 = v0 - zp0, d1 = v1 - zp1;
                lsum += d0 * d0 + d1 * d1;
            }
        }
        __syncthreads();   // Abf reads done; safe to restage

        if (T == 0) {
            ushort4v pk0, pk1;
            #pragma unroll
            for (int j = 0; j < 4; ++j) { pk0[j] = f2bf(z1v[j]); pk1[j] = f2bf(z1v[4 + j]); }
            *(ushort4v*)&Abf[r * 72 + cg * 8]     = pk0;
            *(ushort4v*)&Abf[r * 72 + cg * 8 + 4] = pk1;
            __syncthreads();
            zoffT += 128;
        }
    }

    // ---- loss: wave reduce -> LDS -> one global atomic per block ----
    #pragma unroll
    for (int d = 1; d < 64; d <<= 1) lsum += __shfl_xor(lsum, d, 64);
    if (l == 0) atomicAdd(&loss_acc, lsum);
    __syncthreads();
    if (t == 0) atomicAdd(out, loss_acc * (1.25f / 4194304.f));  // (1+BETA)/numel
}

extern "C" void kernel_launch(void* const* d_in, const int* in_sizes, int n_in,
                              void* d_out, int out_size, void* d_ws, size_t ws_size,
                              hipStream_t stream) {
    (void)in_sizes; (void)n_in; (void)out_size; (void)ws_size;
    const float* z  = (const float*)d_in[0];
    const float* cb = (const float*)d_in[1];
    float* out = (float*)d_out;
    ushort* cbb = (ushort*)d_ws;
    float* negbias = (float*)((char*)d_ws + K_CODES * CDIM * sizeof(ushort));

    prep_kernel<<<dim3(256), dim3(256), 0, stream>>>(cb, cbb, negbias, out);
    vq_kernel<<<dim3(256), dim3(1024), 0, stream>>>(z, cbb, negbias, out);
}